// Round 11
// baseline (992.603 us; speedup 1.0000x reference)
//
#include <hip/hip_runtime.h>
#include <math.h>

#define NWAY 5
#define NSUP 25
#define NZV  125
#define DF   640
#define NQ   75

// =====================================================================
// Fast transform: tf(x) = sign(x) * (g(|x|+1e-5) - g(1e-5)),
//   g(t) = ln(1/t+1)^{-1.3} = exp2(-1.3*log2(log2(1/t+1)) + A),
//   A = -1.3*log2(ln2) = 0.68739628.
// =====================================================================
__device__ __forceinline__ float gfun(float t) {
  const float l2 = __log2f(__builtin_amdgcn_rcpf(t) + 1.0f);
  return __builtin_amdgcn_exp2f(fmaf(-1.3f, __log2f(l2), 0.68739628f));
}
__device__ __forceinline__ float simple_tf(float x, float Cg) {
  const float s = gfun(fabsf(x) + 1e-5f) - Cg;
  return (x >= 0.0f) ? s : -s;
}

// wave-wide reductions (uniform result on all lanes)
__device__ __forceinline__ double wrmin(double v) {
#pragma unroll
  for (int off = 32; off > 0; off >>= 1) v = fmin(v, __shfl_xor(v, off));
  return v;
}
__device__ __forceinline__ double wrsum(double v) {
#pragma unroll
  for (int off = 32; off > 0; off >>= 1) v += __shfl_xor(v, off);
  return v;
}

// =====================================================================
// In-place GJ of 25x25 SPD, columns on lanes. Supports a PAIR of
// matrices simultaneously: lanes 0-24 = matrix A cols, lanes 32-56 =
// matrix B cols; broadcast source = J + (lane & 32). R4-verified math.
// =====================================================================
__device__ __forceinline__ void gj25(double (&a)[25], const int lane) {
  const int lm = lane & 32;
#pragma unroll
  for (int J = 0; J < 25; ++J) {
    const int sel = J + lm;
    const double djj = __shfl(a[J], sel);
    const double pinv = 1.0 / djj;
    const bool piv = (lane == sel);
    const double aJ = (piv ? 1.0 : a[J]) * pinv;
#pragma unroll
    for (int r = 0; r < 25; ++r) {
      if (r != J) {
        const double f = __shfl(a[r], sel);
        a[r] = (piv ? 0.0 : a[r]) - f * aJ;
      }
    }
    a[J] = aJ;
  }
}

// Factorize on ONE wave: HI[k] = (M+diag(d_k))^-1 (paired GJ rounds),
// WI = (sum_k HI[k])^-1. noinline: needs ~70 VGPR < default budget, and
// keeps the fat GJ code emitted once.
__device__ __attribute__((noinline)) void fact1w(const double* Msh,
                                                 const double* DDv, double* HI,
                                                 double* WI, const int lane) {
#pragma unroll 1
  for (int rd = 0; rd < 3; ++rd) {
    const int kk = 2 * rd + ((lane < 32) ? 0 : 1);
    const int c = (lane < 32) ? lane : lane - 32;
    const bool act = (c < 25) && (kk < 5);
    double a[25];
#pragma unroll
    for (int j = 0; j < 25; ++j) a[j] = 1.0;
    if (act) {
#pragma unroll
      for (int j = 0; j < 25; ++j)
        a[j] = Msh[c * 26 + j] + ((j == c) ? DDv[c * 5 + kk] : 0.0);
    }
    gj25(a, lane);
    if (act) {
#pragma unroll
      for (int i = 0; i < 25; ++i) HI[kk * 650 + i * 26 + c] = a[i];
    }
  }
  {
    double a[25];
#pragma unroll
    for (int j = 0; j < 25; ++j) a[j] = 1.0;
    if (lane < 25) {
#pragma unroll
      for (int r = 0; r < 25; ++r) {
        double acc = 0.0;
#pragma unroll
        for (int k = 0; k < 5; ++k) acc += HI[k * 650 + r * 26 + lane];
        a[r] = acc;
      }
    }
    gj25(a, lane);
    if (lane < 25) {
#pragma unroll
      for (int i = 0; i < 25; ++i) WI[i * 26 + lane] = a[i];
    }
  }
}

// KKT solve on ONE wave. Element v0=lane, v1=64+lane (lane<61).
// ZRS: rs==0; ZR: rx=rz=ry==0. dy left in DYW (caller accumulates).
template <bool ZRS, bool ZR>
__device__ __forceinline__ void kkt1w(
    const double (&Mr0)[25], const double (&Mr1)[25], const double* HI,
    const double* WI, double* TT, double* C1, double* C2v, double* VV,
    double* GG, double* DYW, double rx0, double rx1, double rs0, double rs1,
    double rz0, double rz1, double ryv, double dd0, double dd1, double& dx0,
    double& dx1, double& ds0, double& ds1, double& dz0, double& dz1,
    const int lane, const int i0, const int k0, const int i1c, const int k1,
    const bool e1ok) {
  const double t0 = (ZR ? 0.0 : rz0) - (ZRS ? 0.0 : rs0 / dd0);
  const double t1 = (ZR ? 0.0 : rz1) - (ZRS ? 0.0 : rs1 / dd1);
  TT[lane] = t0;
  if (e1ok) TT[64 + lane] = t1;
  double c10 = ZR ? 0.0 : -rx0;
  double c11 = ZR ? 0.0 : -rx1;
#pragma unroll
  for (int j = 0; j < 25; ++j) {
    c10 += Mr0[j] * TT[j * 5 + k0];
    c11 += Mr1[j] * TT[j * 5 + k1];
  }
  C1[lane] = c10;
  if (e1ok) C1[64 + lane] = c11;
  if (lane < 25) {
    double acc = ZR ? 0.0 : -ryv;
#pragma unroll
    for (int k = 0; k < 5; ++k) acc += TT[lane * 5 + k];
    C2v[lane] = acc;
  }
  double vv0 = 0.0, vv1 = 0.0;
#pragma unroll
  for (int j = 0; j < 25; ++j) {
    vv0 += HI[k0 * 650 + i0 * 26 + j] * C1[j * 5 + k0];
    vv1 += HI[k1 * 650 + i1c * 26 + j] * C1[j * 5 + k1];
  }
  VV[lane] = vv0;
  if (e1ok) VV[64 + lane] = vv1;
  if (lane < 25) {
    double acc = -C2v[lane];
#pragma unroll
    for (int k = 0; k < 5; ++k) acc += VV[lane * 5 + k];
    GG[lane] = acc;
  }
  if (lane < 25) {
    double acc = 0.0;
#pragma unroll
    for (int r = 0; r < 25; ++r) acc += WI[lane * 26 + r] * GG[r];
    DYW[lane] = acc;
  }
  double h0 = 0.0, h1 = 0.0;
#pragma unroll
  for (int j = 0; j < 25; ++j) {
    h0 += HI[k0 * 650 + i0 * 26 + j] * DYW[j];
    h1 += HI[k1 * 650 + i1c * 26 + j] * DYW[j];
  }
  const double u0 = vv0 - h0, u1 = vv1 - h1;
  dz0 = dd0 * u0;
  dx0 = u0 - t0;
  ds0 = ((ZRS ? 0.0 : -rs0) - dz0) / dd0;
  dz1 = dd1 * u1;
  dx1 = u1 - t1;
  ds1 = ((ZRS ? 0.0 : -rs1) - dz1) / dd1;
}

// stage 64 cols of transformed+normalized train rows into GBUF[25][68]
__device__ __forceinline__ void stage_chunk(const float* __restrict__ tb,
                                            const int ch, const bool us,
                                            const float Cg, const float* invn,
                                            float* GBUF, const int tid) {
  for (int idx = tid; idx < 1600; idx += 320) {
    const int r = idx >> 6, cc = idx & 63;
    float v = tb[r * DF + (ch << 6) + cc];
    if (us) v = simple_tf(v, Cg);
    GBUF[r * 68 + cc] = v * invn[r];
  }
}

// =====================================================================
// qp_kernel: 320 threads. Phases 1-2 (norms, Gram->Msh) use 5 waves.
// The ENTIRE interior-point QP then runs on wave 0 with ZERO block
// barriers (intra-wave LDS ordering only) — the R10 kernel spent its
// 260us on ~100 barrier-separated micro-phases. Phase 4 (xf) uses all
// 5 waves again.
// =====================================================================
__global__ void __launch_bounds__(320, 1) qp_kernel(
    const float* __restrict__ train, const int* __restrict__ usimple,
    float* __restrict__ xfg) {
  const int b = blockIdx.x;
  const int tid = threadIdx.x;
  const int lane = tid & 63;
  const int wv = tid >> 6;
  const bool us = (usimple[0] != 0);
  const float Cg = gfun(1e-5f);

  __shared__ double HI[5 * 650];   // Hinv stash; aliased by GBUF
  __shared__ double WI[650];
  __shared__ double Msh[650];
  __shared__ double TT[125], C1[125], VV[125], Xv[125], DDv[125];
  __shared__ double YV[25], C2v[25], GG[25], DYW[25];
  __shared__ float invn[25];
  __shared__ float bxs[125];
  float* GBUF = (float*)HI;   // 6800 B < 26000 B

  const float* tb = train + (size_t)b * NSUP * DF;

  // ---- phase 1: row norms (5 waves) ----
#pragma unroll
  for (int jj = 0; jj < 5; ++jj) {
    const int r = wv * 5 + jj;
    float ss = 0.0f;
#pragma unroll
    for (int c = 0; c < 10; ++c) {
      float v = tb[r * DF + lane + 64 * c];
      if (us) v = simple_tf(v, Cg);
      ss += v * v;
    }
#pragma unroll
    for (int off = 32; off > 0; off >>= 1) ss += __shfl_xor(ss, off);
    if (lane == 0) invn[r] = 1.0f / fmaxf(sqrtf(ss), 1e-12f);
  }
  __syncthreads();

  // ---- phase 2: chunked Gram -> Msh = FT FT^T + I (5 waves) ----
  int i1p, j1p, i2p = 0, j2p = 0;
  {
    int rem = tid, i = 0;
    while (rem >= NSUP - i) { rem -= NSUP - i; ++i; }
    i1p = i; j1p = i + rem;
  }
  if (tid < 5) {
    int rem = 320 + tid, i = 0;
    while (rem >= NSUP - i) { rem -= NSUP - i; ++i; }
    i2p = i; j2p = i + rem;
  }
  double acc1 = 0.0, acc2 = 0.0;
  for (int ch = 0; ch < 10; ++ch) {
    stage_chunk(tb, ch, us, Cg, invn, GBUF, tid);
    __syncthreads();
    {
      const float4* ra = (const float4*)(GBUF + i1p * 68);
      const float4* rb = (const float4*)(GBUF + j1p * 68);
#pragma unroll
      for (int c = 0; c < 16; ++c) {
        float4 av = ra[c], bv = rb[c];
        acc1 += (double)av.x * bv.x + (double)av.y * bv.y +
                (double)av.z * bv.z + (double)av.w * bv.w;
      }
    }
    if (tid < 5) {
      const float4* ra = (const float4*)(GBUF + i2p * 68);
      const float4* rb = (const float4*)(GBUF + j2p * 68);
#pragma unroll
      for (int c = 0; c < 16; ++c) {
        float4 av = ra[c], bv = rb[c];
        acc2 += (double)av.x * bv.x + (double)av.y * bv.y +
                (double)av.z * bv.z + (double)av.w * bv.w;
      }
    }
    __syncthreads();
  }
  if (i1p == j1p) acc1 += 1.0;
  Msh[i1p * 26 + j1p] = acc1;
  if (i1p != j1p) Msh[j1p * 26 + i1p] = acc1;
  if (tid < 5) {
    if (i2p == j2p) acc2 += 1.0;
    Msh[i2p * 26 + j2p] = acc2;
    if (i2p != j2p) Msh[j2p * 26 + i2p] = acc2;
  }
  __syncthreads();

  // ---- phase 3: QP on wave 0 only, no block barriers ----
  if (wv == 0) {
    const int i0 = lane / 5, k0 = lane - 5 * (lane / 5);
    const int v1 = 64 + lane;
    const bool e1ok = (lane < 61);
    const int i1 = v1 / 5, k1 = v1 - 5 * (v1 / 5);
    const int i1c = e1ok ? i1 : 0;

    double Mr0[25], Mr1[25];
#pragma unroll
    for (int j = 0; j < 25; ++j) {
      Mr0[j] = Msh[i0 * 26 + j];
      Mr1[j] = Msh[i1c * 26 + j];
    }

    const double oh0 = (k0 == (i0 % 5)) ? 1.0 : 0.0;
    const double oh1 = (k1 == (i1c % 5)) ? 1.0 : 0.0;
    double dd0 = 1.0, dd1 = 1.0;
    DDv[lane] = 1.0;
    if (e1ok) DDv[v1] = 1.0;
    double rx0 = -oh0, rx1 = -oh1;
    double rz0 = -0.1 * oh0, rz1 = -0.1 * oh1;
    double ryv = 0.0;
    double bestres = 1e300;

    fact1w(Msh, DDv, HI, WI, lane);
    double x0, x1, s0, s1, z0, z1;
    kkt1w<true, false>(Mr0, Mr1, HI, WI, TT, C1, C2v, VV, GG, DYW, rx0, rx1,
                       0.0, 0.0, rz0, rz1, ryv, dd0, dd1, x0, x1, s0, s1, z0,
                       z1, lane, i0, k0, i1c, k1, e1ok);
    double yvr = (lane < 25) ? DYW[lane] : 0.0;
    if (lane < 25) YV[lane] = yvr;
    Xv[lane] = x0;
    if (e1ok) Xv[v1] = x1;

    // shift(s), shift(z)
    {
      const double ms = wrmin(fmin(s0, e1ok ? s1 : 1e300));
      if (ms < 0.0) { s0 -= (ms - 1.0); s1 -= (ms - 1.0); }
      const double mz = wrmin(fmin(z0, e1ok ? z1 : 1e300));
      if (mz < 0.0) { z0 -= (mz - 1.0); z1 -= (mz - 1.0); }
    }
    bxs[lane] = (float)x0;
    if (e1ok) bxs[v1] = (float)x1;

#pragma unroll 1
    for (int it = 0; it < 3; ++it) {
      // residuals (Xv, YV up to date)
      double mx0 = 0.0, mx1 = 0.0;
#pragma unroll
      for (int j = 0; j < 25; ++j) {
        mx0 += Mr0[j] * Xv[j * 5 + k0];
        mx1 += Mr1[j] * Xv[j * 5 + k1];
      }
      rx0 = YV[i0] + z0 + mx0 - oh0;
      rx1 = YV[i1c] + z1 + mx1 - oh1;
      rz0 = x0 + s0 - 0.1 * oh0;
      rz1 = x1 + s1 - 0.1 * oh1;
      if (lane < 25) {
        double acc = 0.0;
#pragma unroll
        for (int k = 0; k < 5; ++k) acc += Xv[lane * 5 + k];
        ryv = acc;
      }
      const double szsum =
          wrsum(s0 * z0 + (e1ok ? s1 * z1 : 0.0));
      const double snx =
          wrsum(rx0 * rx0 + (e1ok ? rx1 * rx1 : 0.0));
      const double snz =
          wrsum(rz0 * rz0 + (e1ok ? rz1 * rz1 : 0.0));
      const double sny = wrsum((lane < 25) ? ryv * ryv : 0.0);
      const double mu = fabs(szsum) / 125.0;
      const double res = sqrt(snz + 1e-30) + sqrt(sny + 1e-30) +
                         sqrt(snx + 1e-30) + 125.0 * mu;
      if (res < bestres) {
        bestres = res;
        bxs[lane] = (float)x0;
        if (e1ok) bxs[v1] = (float)x1;
      }
      if (it == 2) break;

      dd0 = z0 / s0;
      dd1 = e1ok ? (z1 / s1) : 1.0;
      DDv[lane] = dd0;
      if (e1ok) DDv[v1] = dd1;
      fact1w(Msh, DDv, HI, WI, lane);

      double dxa0, dxa1, dsa0, dsa1, dza0, dza1;
      kkt1w<false, false>(Mr0, Mr1, HI, WI, TT, C1, C2v, VV, GG, DYW, rx0,
                          rx1, z0, z1, rz0, rz1, ryv, dd0, dd1, dxa0, dxa1,
                          dsa0, dsa1, dza0, dza1, lane, i0, k0, i1c, k1,
                          e1ok);
      double dya = (lane < 25) ? DYW[lane] : 0.0;

      double st0 = fmin((dza0 < 0.0) ? (-z0 / dza0) : 1e12,
                        (dsa0 < 0.0) ? (-s0 / dsa0) : 1e12);
      double st1 = fmin((dza1 < 0.0) ? (-z1 / dza1) : 1e12,
                        (dsa1 < 0.0) ? (-s1 / dsa1) : 1e12);
      const double aff = fmin(wrmin(fmin(st0, e1ok ? st1 : 1e300)), 1.0);
      const double num =
          wrsum((s0 + aff * dsa0) * (z0 + aff * dza0) +
                (e1ok ? (s1 + aff * dsa1) * (z1 + aff * dza1) : 0.0));
      const double sg = num / szsum;
      const double musig = mu * (sg * sg * sg);
      const double rsc0 = (-musig + dsa0 * dza0) / s0;
      const double rsc1 = e1ok ? ((-musig + dsa1 * dza1) / s1) : 0.0;

      double dxc0, dxc1, dsc0, dsc1, dzc0, dzc1;
      kkt1w<false, true>(Mr0, Mr1, HI, WI, TT, C1, C2v, VV, GG, DYW, 0.0,
                         0.0, rsc0, rsc1, 0.0, 0.0, 0.0, dd0, dd1, dxc0,
                         dxc1, dsc0, dsc1, dzc0, dzc1, lane, i0, k0, i1c, k1,
                         e1ok);
      if (lane < 25) dya += DYW[lane];
      dxa0 += dxc0; dsa0 += dsc0; dza0 += dzc0;
      dxa1 += dxc1; dsa1 += dsc1; dza1 += dzc1;

      st0 = fmin((dza0 < 0.0) ? (-z0 / dza0) : 1e12,
                 (dsa0 < 0.0) ? (-s0 / dsa0) : 1e12);
      st1 = fmin((dza1 < 0.0) ? (-z1 / dza1) : 1e12,
                 (dsa1 < 0.0) ? (-s1 / dsa1) : 1e12);
      const double al =
          fmin(0.999 * wrmin(fmin(st0, e1ok ? st1 : 1e300)), 1.0);
      x0 += al * dxa0; s0 += al * dsa0; z0 += al * dza0;
      x1 += al * dxa1; s1 += al * dsa1; z1 += al * dza1;
      if (lane < 25) {
        yvr += al * dya;
        YV[lane] = yvr;
      }
      Xv[lane] = x0;
      if (e1ok) Xv[v1] = x1;
    }
  }
  __syncthreads();

  // ---- phase 4: xf[w][d] = sum_s bxs[s,w] * FT[s][d] (5 waves) ----
  float xs[25];
#pragma unroll
  for (int s_ = 0; s_ < 25; ++s_) xs[s_] = bxs[s_ * 5 + wv];
  for (int ch = 0; ch < 10; ++ch) {
    stage_chunk(tb, ch, us, Cg, invn, GBUF, tid);
    __syncthreads();
    float acc = 0.0f;
#pragma unroll
    for (int s_ = 0; s_ < 25; ++s_) acc += xs[s_] * GBUF[s_ * 68 + lane];
    xfg[((size_t)b * NWAY + wv) * DF + (ch << 6) + lane] = acc;
    __syncthreads();
  }
}

// =====================================================================
// Output kernel: 640 threads, TWO batches per block (waves 0-4 / 5-9),
// grid B/2 = 256 -> single round. out[q][w] = (fq/|fq|).xf[w].
// =====================================================================
__global__ void __launch_bounds__(640, 1) out_kernel(
    const float* __restrict__ test, const int* __restrict__ usimple,
    const float* __restrict__ xfg, float* __restrict__ out, const int B) {
  const int tid = threadIdx.x;
  const int half = tid >= 320 ? 1 : 0;
  const int tl = tid - 320 * half;
  const int lane = tid & 63;
  const int u = tl >> 6;   // 0..4
  const int b = 2 * blockIdx.x + half;
  const bool live = b < B;
  const bool us = (usimple[0] != 0);
  const float Cg = gfun(1e-5f);

  __shared__ float xfs_[2][NWAY * DF];
  float* xfs = xfs_[half];
  const size_t bsafe = (size_t)(live ? b : 0);
  for (int i = tl; i < NWAY * DF; i += 320)
    xfs[i] = xfg[bsafe * NWAY * DF + i];
  __syncthreads();

  const float* qb = test + bsafe * NQ * DF;
#pragma unroll 1
  for (int jj = 0; jj < 15; ++jj) {
    const int q = u + 5 * jj;
    const float* qr = qb + (size_t)q * DF;
    float nrm = 0.0f, a0 = 0.0f, a1 = 0.0f, a2 = 0.0f, a3 = 0.0f, a4 = 0.0f;
#pragma unroll
    for (int c = 0; c < 10; ++c) {
      const int d = lane + 64 * c;
      float v = qr[d];
      if (us) v = simple_tf(v, Cg);
      nrm += v * v;
      a0 += v * xfs[0 * DF + d];
      a1 += v * xfs[1 * DF + d];
      a2 += v * xfs[2 * DF + d];
      a3 += v * xfs[3 * DF + d];
      a4 += v * xfs[4 * DF + d];
    }
#pragma unroll
    for (int off = 32; off > 0; off >>= 1) {
      nrm += __shfl_xor(nrm, off);
      a0 += __shfl_xor(a0, off);
      a1 += __shfl_xor(a1, off);
      a2 += __shfl_xor(a2, off);
      a3 += __shfl_xor(a3, off);
      a4 += __shfl_xor(a4, off);
    }
    if (lane == 0 && live) {
      const float sc = 1.0f / fmaxf(sqrtf(nrm), 1e-12f);
      float* op = out + ((size_t)b * NQ + q) * 5;
      op[0] = a0 * sc;
      op[1] = a1 * sc;
      op[2] = a2 * sc;
      op[3] = a3 * sc;
      op[4] = a4 * sc;
    }
  }
}

// =====================================================================
extern "C" void kernel_launch(void* const* d_in, const int* in_sizes, int n_in,
                              void* d_out, int out_size, void* d_ws,
                              size_t ws_size, hipStream_t stream) {
  const float* ftest = (const float*)d_in[0];
  const float* ftrain = (const float*)d_in[1];
  const int* usimple = (const int*)d_in[4];
  float* out = (float*)d_out;
  const int B = in_sizes[1] / (NSUP * DF);

  float* xfg = (float*)d_ws;  // B * 5 * 640 floats

  qp_kernel<<<dim3(B), dim3(320), 0, stream>>>(ftrain, usimple, xfg);
  out_kernel<<<dim3((B + 1) / 2), dim3(640), 0, stream>>>(ftest, usimple,
                                                          xfg, out, B);
}

// Round 12
// 483.028 us; speedup vs baseline: 2.0550x; 2.0550x over previous
//
#include <hip/hip_runtime.h>
#include <math.h>

#define NWAY 5
#define NSUP 25
#define NZV  125
#define DF   640
#define NQ   75
#define TPB  640   // two batches per block: waves 0-4 batch A, 5-9 batch B

// =====================================================================
// Fast transform: tf(x) = sign(x) * (g(|x|+1e-5) - g(1e-5)),
//   g(t) = ln(1/t+1)^{-1.3} = exp2(-1.3*log2(log2(1/t+1)) + A),
//   A = -1.3*log2(ln2) = 0.68739628. 4 transcendentals vs reference's 8.
// =====================================================================
__device__ __forceinline__ float gfun(float t) {
  const float l2 = __log2f(__builtin_amdgcn_rcpf(t) + 1.0f);
  return __builtin_amdgcn_exp2f(fmaf(-1.3f, __log2f(l2), 0.68739628f));
}
__device__ __forceinline__ float simple_tf(float x, float Cg) {
  const float s = gfun(fabsf(x) + 1e-5f) - Cg;
  return (x >= 0.0f) ? s : -s;
}

// Constant-lane fp64 broadcast via v_readlane (VALU, off the LDS pipe).
__device__ __forceinline__ double bcastd(double v, const int srclane) {
  const int lo = __builtin_amdgcn_readlane(__double2loint(v), srclane);
  const int hi = __builtin_amdgcn_readlane(__double2hiint(v), srclane);
  return __hiloint2double(hi, lo);
}

// In-place Gauss-Jordan of 25x25 SPD; columns live on lanes BASE..BASE+24.
template <int BASE, int J>
__device__ __forceinline__ void gjp(double (&a)[25], const int lane,
                                    const bool act) {
  const double djj = bcastd(a[J], BASE + J);
  const double pinv = 1.0 / djj;
  if (act) a[J] = ((lane == BASE + J) ? 1.0 : a[J]) * pinv;
#pragma unroll
  for (int r = 0; r < 25; ++r) {
    if (r != J) {
      const double f = bcastd(a[r], BASE + J);
      if (act) a[r] = ((lane == BASE + J) ? 0.0 : a[r]) - f * a[J];
    }
  }
}
template <int BASE, int J = 0>
__device__ __forceinline__ void gjall(double (&a)[25], const int lane,
                                      const bool act) {
  if constexpr (J < 25) {
    gjp<BASE, J>(a, lane, act);
    gjall<BASE, J + 1>(a, lane, act);
  }
}

// Factorize (per half): hv <- row `lane` of Hinv_w; this half's wave-0
// lanes 32-56 additionally get Winv = (sum_k Hinv_k)^-1 rows.
__device__ __forceinline__ void factorize(const double* Msh, const double* dd,
                                          double* W, double (&hv)[25],
                                          const int tl, const int lane,
                                          const int w) {
  if (lane < 25) {
#pragma unroll
    for (int j = 0; j < 25; ++j)
      hv[j] = Msh[lane * 26 + j] + ((j == lane) ? dd[lane * 5 + w] : 0.0);
  }
  gjall<0>(hv, lane, true);
  for (int i2 = tl; i2 < 650; i2 += 320) W[i2] = 0.0;
  __syncthreads();
#pragma unroll
  for (int k = 0; k < 5; ++k) {
    if (w == k && lane < 25) {
#pragma unroll
      for (int j = 0; j < 25; ++j) W[lane * 26 + j] += hv[j];
    }
    __syncthreads();
  }
  if (w == 0) {
    if (lane >= 32 && lane < 57) {
#pragma unroll
      for (int r = 0; r < 25; ++r) hv[r] = W[(lane - 32) * 26 + r];
    }
    gjall<32>(hv, lane, lane >= 32 && lane < 57);
  }
  // next consumer phase begins with its own __syncthreads()
}

// KKT solve (per half). ZRS: rs==0; ZR: rx=rz=ry==0; ACC: accumulate.
// dyw: scratch for THIS solve's dy.
template <bool ZRS, bool ZR, bool ACC>
__device__ __forceinline__ void kkt_solve(
    const double* Msh, const double* dd, double* tt, double* c1, double* c2,
    double* vv, double* gg, double* dyw, const double* rx, const double* rs,
    const double* rz, const double* ry, double (&hv)[25], double* dx,
    double* ds, double* dz, double* dy, const int tl, const int lane,
    const int w) {
  if (tl < NZV) {
    double t = ZR ? 0.0 : rz[tl];
    if (!ZRS) t -= rs[tl] / dd[tl];
    tt[tl] = t;
  }
  __syncthreads();
  if (tl < NZV) {
    const int i = tl / 5, k = tl - i * 5;
    double acc = ZR ? 0.0 : -rx[tl];
#pragma unroll
    for (int j = 0; j < 25; ++j) acc += Msh[i * 26 + j] * tt[j * 5 + k];
    c1[tl] = acc;
  } else if (tl >= 128 && tl < 153) {
    const int i = tl - 128;
    double acc = ZR ? 0.0 : -ry[i];
#pragma unroll
    for (int k = 0; k < 5; ++k) acc += tt[i * 5 + k];
    c2[i] = acc;
  }
  __syncthreads();
  if (lane < 25) {
    double acc = 0.0;
#pragma unroll
    for (int j = 0; j < 25; ++j) acc += hv[j] * c1[j * 5 + w];
    vv[lane * 5 + w] = acc;
  }
  __syncthreads();
  if (w == 0) {  // gg then dy in the SAME wave: LDS program order suffices
    if (lane < 25) {
      double acc = -c2[lane];
#pragma unroll
      for (int k = 0; k < 5; ++k) acc += vv[lane * 5 + k];
      gg[lane] = acc;
    }
    if (lane >= 32 && lane < 57) {
      double acc = 0.0;
#pragma unroll
      for (int r = 0; r < 25; ++r) acc += hv[r] * gg[r];
      dyw[lane - 32] = acc;
      if (ACC) dy[lane - 32] += acc; else dy[lane - 32] = acc;
    }
  }
  __syncthreads();
  if (lane < 25) {
    double acc = 0.0;
#pragma unroll
    for (int j = 0; j < 25; ++j) acc += hv[j] * dyw[j];
    const int v = lane * 5 + w;
    const double u = vv[v] - acc;
    const double dzv = dd[v] * u;
    const double dxv = u - tt[v];
    const double dsv = ((ZRS ? 0.0 : -rs[v]) - dzv) / dd[v];
    if (ACC) { dz[v] += dzv; dx[v] += dxv; ds[v] += dsv; }
    else     { dz[v]  = dzv; dx[v]  = dxv; ds[v]  = dsv; }
  }
  __syncthreads();
}

// Per-half block reduction: first wave of the half reduces buf[0..n).
__device__ __forceinline__ double bred(const double* buf, int n, int ismin,
                                       double* SCh, const int w,
                                       const int lane) {
  __syncthreads();
  if (w == 0) {
    double acc = ismin ? 1e300 : 0.0;
    for (int m = lane; m < n; m += 64) {
      const double v = buf[m];
      acc = ismin ? fmin(acc, v) : (acc + v);
    }
#pragma unroll
    for (int off = 32; off > 0; off >>= 1) {
      const double o = __shfl_xor(acc, off);
      acc = ismin ? fmin(acc, o) : (acc + o);
    }
    if (lane == 0) SCh[15] = acc;
  }
  __syncthreads();
  return SCh[15];
}

// stage 64 columns of transformed+normalized train rows into GBUF[25][68]
__device__ __forceinline__ void stage_chunk(const float* __restrict__ tb,
                                            const int ch, const bool us,
                                            const float Cg,
                                            const float* invn, float* GBUF,
                                            const int tl) {
  for (int idx = tl; idx < 1600; idx += 320) {
    const int r = idx >> 6, cc = idx & 63;
    float v = tb[r * DF + (ch << 6) + cc];
    if (us) v = simple_tf(v, Cg);
    GBUF[r * 68 + cc] = v * invn[r];
  }
}

// =====================================================================
// Fused kernel: TWO batches per 640-thread block (waves 0-4 / 5-9).
// Phases: norms -> Gram -> QP (R10 structure, verified) -> xf to LDS ->
// fused output (queries) straight to `out`. The R10 split version spent
// ~186us on the second dispatch + xfg round-trip + another 1-block/CU
// latency-exposed kernel; the fused phase-5 costs ~15us of block time.
// =====================================================================
__global__ void __launch_bounds__(TPB, 2) qp_kernel(
    const float* __restrict__ train, const float* __restrict__ test,
    const int* __restrict__ usimple, float* __restrict__ out, const int B) {
  const int tid = threadIdx.x;
  const int half = tid >= 320 ? 1 : 0;
  const int tl = tid - 320 * half;
  const int lane = tid & 63;
  const int w = tl >> 6;
  const int bb = 2 * blockIdx.x + half;
  const bool live = bb < B;
  const bool us = (usimple[0] != 0);
  const float Cg = gfun(1e-5f);

  __shared__ double Msh_[2][650];
  __shared__ __align__(16) unsigned char GBW_[2][6800];
  __shared__ double x_[2][125], s_[2][125], z_[2][125], rx_[2][125],
      rz_[2][125], dd_[2][125], tt_[2][125], c1_[2][125], vv_[2][125],
      dxa_[2][125], dsa_[2][125], dza_[2][125], rsc_[2][125];
  __shared__ double yv_[2][25], ry_[2][25], c2_[2][25], gg_[2][25],
      dya_[2][25], dyw_[2][25];
  __shared__ double SC_[2][16];
  __shared__ float invn_[2][25];
  __shared__ float bxs_[2][125];
  __shared__ float xfs_[2][NWAY * DF];   // fused-output staging

  double* Msh = Msh_[half];
  double* W = (double*)GBW_[half];
  float* GBUF = (float*)GBW_[half];
  double* x = x_[half];
  double* s = s_[half];
  double* z = z_[half];
  double* rx = rx_[half];
  double* rz = rz_[half];
  double* dd = dd_[half];
  double* tt = tt_[half];
  double* c1 = c1_[half];
  double* vv = vv_[half];
  double* dxa = dxa_[half];
  double* dsa = dsa_[half];
  double* dza = dza_[half];
  double* rsc = rsc_[half];
  double* yv = yv_[half];
  double* ry = ry_[half];
  double* c2 = c2_[half];
  double* gg = gg_[half];
  double* dya = dya_[half];
  double* dyw = dyw_[half];
  double* SC = SC_[half];
  float* invn = invn_[half];
  float* bxs = bxs_[half];
  float* xfs = xfs_[half];
  double hv[25];

  const float* tb = train + (size_t)(live ? bb : 0) * NSUP * DF;

  // ---- phase 1: row norms ----
#pragma unroll
  for (int jj = 0; jj < 5; ++jj) {
    const int r = w * 5 + jj;
    float ss = 0.0f;
#pragma unroll
    for (int c = 0; c < 10; ++c) {
      float v = tb[r * DF + lane + 64 * c];
      if (us) v = simple_tf(v, Cg);
      ss += v * v;
    }
#pragma unroll
    for (int off = 32; off > 0; off >>= 1) ss += __shfl_xor(ss, off);
    if (lane == 0) invn[r] = 1.0f / fmaxf(sqrtf(ss), 1e-12f);
  }
  __syncthreads();

  // ---- phase 2: chunked Gram, M = FT FT^T + I (fp64 accumulate) ----
  int i1, j1, i2v = 0, j2v = 0;
  {
    int rem = tl, i = 0;
    while (rem >= NSUP - i) { rem -= NSUP - i; ++i; }
    i1 = i; j1 = i + rem;
  }
  if (tl < 5) {
    int rem = 320 + tl, i = 0;
    while (rem >= NSUP - i) { rem -= NSUP - i; ++i; }
    i2v = i; j2v = i + rem;
  }
  double acc1 = 0.0, acc2 = 0.0;
  for (int ch = 0; ch < 10; ++ch) {
    stage_chunk(tb, ch, us, Cg, invn, GBUF, tl);
    __syncthreads();
    {
      const float4* ra = (const float4*)(GBUF + i1 * 68);
      const float4* rb = (const float4*)(GBUF + j1 * 68);
#pragma unroll
      for (int c = 0; c < 16; ++c) {
        float4 av = ra[c], bv = rb[c];
        acc1 += (double)av.x * bv.x + (double)av.y * bv.y +
                (double)av.z * bv.z + (double)av.w * bv.w;
      }
    }
    if (tl < 5) {
      const float4* ra = (const float4*)(GBUF + i2v * 68);
      const float4* rb = (const float4*)(GBUF + j2v * 68);
#pragma unroll
      for (int c = 0; c < 16; ++c) {
        float4 av = ra[c], bv = rb[c];
        acc2 += (double)av.x * bv.x + (double)av.y * bv.y +
                (double)av.z * bv.z + (double)av.w * bv.w;
      }
    }
    __syncthreads();
  }
  if (i1 == j1) acc1 += 1.0;
  Msh[i1 * 26 + j1] = acc1;
  if (i1 != j1) Msh[j1 * 26 + i1] = acc1;
  if (tl < 5) {
    if (i2v == j2v) acc2 += 1.0;   // pairs 322/324 are diagonal
    Msh[i2v * 26 + j2v] = acc2;
    if (i2v != j2v) Msh[j2v * 26 + i2v] = acc2;
  }

  // ---- phase 3: QP ----
  if (tl < NZV) {
    const int i = tl / 5, k = tl - i * 5;
    const double oh = (k == (i % 5)) ? 1.0 : 0.0;
    rx[tl] = -oh;
    rz[tl] = -0.1 * oh;
    dd[tl] = 1.0;
  } else if (tl >= 128 && tl < 153) {
    ry[tl - 128] = 0.0;
  }
  if (tl == 0) SC[0] = 1e300;
  __syncthreads();

  factorize(Msh, dd, W, hv, tl, lane, w);
  kkt_solve<true, false, false>(Msh, dd, tt, c1, c2, vv, gg, dyw, rx,
                                (const double*)nullptr, rz, ry, hv, x, s, z,
                                yv, tl, lane, w);
  {
    const double ms = bred(s, NZV, 1, SC, w, lane);
    if (ms < 0.0 && tl < NZV) s[tl] -= (ms - 1.0);
    const double mz = bred(z, NZV, 1, SC, w, lane);
    if (mz < 0.0 && tl < NZV) z[tl] -= (mz - 1.0);
  }
  if (tl < NZV) bxs[tl] = (float)x[tl];

#pragma unroll 1
  for (int it = 0; it < 3; ++it) {
    __syncthreads();
    if (tl < NZV) {
      const int i = tl / 5, k = tl - i * 5;
      double acc = 0.0;
#pragma unroll
      for (int j = 0; j < 25; ++j) acc += Msh[i * 26 + j] * x[j * 5 + k];
      const double oh = (k == (i % 5)) ? 1.0 : 0.0;
      rx[tl] = yv[i] + z[tl] + acc - oh;
      rz[tl] = x[tl] + s[tl] - 0.1 * oh;
    } else if (tl >= 128 && tl < 153) {
      const int i = tl - 128;
      double acc = 0.0;
#pragma unroll
      for (int k = 0; k < 5; ++k) acc += x[i * 5 + k];
      ry[i] = acc;
    }
    __syncthreads();
    if (w == 0) {  // per-half consolidated 4-sum reduction (first wave)
      double s1 = 0, s2 = 0, s3 = 0, s4 = 0;
      for (int m = lane; m < 125; m += 64) {
        s1 += s[m] * z[m];
        s2 += rx[m] * rx[m];
        s3 += rz[m] * rz[m];
      }
      if (lane < 25) s4 = ry[lane] * ry[lane];
#pragma unroll
      for (int off = 32; off > 0; off >>= 1) {
        s1 += __shfl_xor(s1, off);
        s2 += __shfl_xor(s2, off);
        s3 += __shfl_xor(s3, off);
        s4 += __shfl_xor(s4, off);
      }
      if (lane == 0) { SC[2] = s1; SC[3] = s2; SC[4] = s3; SC[5] = s4; }
    }
    __syncthreads();
    const double szsum = SC[2];
    const double mu = fabs(szsum) / 125.0;
    const double res = sqrt(SC[4] + 1e-30) + sqrt(SC[5] + 1e-30) +
                       sqrt(SC[3] + 1e-30) + 125.0 * mu;
    if (tl == 0) {
      if (res < SC[0]) { SC[0] = res; SC[1] = 1.0; } else SC[1] = 0.0;
    }
    __syncthreads();
    if (SC[1] != 0.0 && tl < NZV) bxs[tl] = (float)x[tl];
    if (it == 2) break;
    __syncthreads();

    if (tl < NZV) dd[tl] = z[tl] / s[tl];
    __syncthreads();
    factorize(Msh, dd, W, hv, tl, lane, w);
    kkt_solve<false, false, false>(Msh, dd, tt, c1, c2, vv, gg, dyw, rx, z,
                                   rz, ry, hv, dxa, dsa, dza, dya, tl, lane,
                                   w);
    if (tl < NZV) {
      const double a1 = (dza[tl] < 0.0) ? (-z[tl] / dza[tl]) : 1e12;
      const double a2 = (dsa[tl] < 0.0) ? (-s[tl] / dsa[tl]) : 1e12;
      tt[tl] = fmin(a1, a2);
    }
    const double aff = fmin(bred(tt, NZV, 1, SC, w, lane), 1.0);
    if (tl < NZV)
      tt[tl] = (s[tl] + aff * dsa[tl]) * (z[tl] + aff * dza[tl]);
    const double num = bred(tt, NZV, 0, SC, w, lane);
    const double sg = num / szsum;
    const double musig = mu * (sg * sg * sg);
    if (tl < NZV) rsc[tl] = (-musig + dsa[tl] * dza[tl]) / s[tl];
    __syncthreads();
    kkt_solve<false, true, true>(Msh, dd, tt, c1, c2, vv, gg, dyw, rx, rsc,
                                 rz, ry, hv, dxa, dsa, dza, dya, tl, lane,
                                 w);
    if (tl < NZV) {
      const double a1 = (dza[tl] < 0.0) ? (-z[tl] / dza[tl]) : 1e12;
      const double a2 = (dsa[tl] < 0.0) ? (-s[tl] / dsa[tl]) : 1e12;
      tt[tl] = fmin(a1, a2);
    }
    const double al = fmin(0.999 * bred(tt, NZV, 1, SC, w, lane), 1.0);
    if (tl < NZV) {
      x[tl] += al * dxa[tl];
      s[tl] += al * dsa[tl];
      z[tl] += al * dza[tl];
    } else if (tl >= 128 && tl < 153) {
      const int i = tl - 128;
      yv[i] += al * dya[i];
    }
  }
  __syncthreads();

  // ---- phase 4: xf[w][d] = sum_s bx[s,w] * FT[s][d] -> LDS ----
  float xs[25];
#pragma unroll
  for (int s_ = 0; s_ < 25; ++s_) xs[s_] = bxs[s_ * 5 + w];
  for (int ch = 0; ch < 10; ++ch) {
    stage_chunk(tb, ch, us, Cg, invn, GBUF, tl);
    __syncthreads();
    float acc = 0.0f;
#pragma unroll
    for (int s_ = 0; s_ < 25; ++s_) acc += xs[s_] * GBUF[s_ * 68 + lane];
    xfs[w * DF + (ch << 6) + lane] = acc;
    __syncthreads();
  }
  // last loop barrier makes all xfs writes visible

  // ---- phase 5 (fused output): out[q][k] = (fq/|fq|).xf[k] ----
  const float* qb = test + (size_t)(live ? bb : 0) * NQ * DF;
#pragma unroll 1
  for (int jj = 0; jj < 15; ++jj) {
    const int q = w + 5 * jj;
    const float* qr = qb + (size_t)q * DF;
    float nrm = 0.0f, a0 = 0.0f, a1 = 0.0f, a2 = 0.0f, a3 = 0.0f, a4 = 0.0f;
#pragma unroll
    for (int c = 0; c < 10; ++c) {
      const int d = lane + 64 * c;
      float v = qr[d];
      if (us) v = simple_tf(v, Cg);
      nrm += v * v;
      a0 += v * xfs[0 * DF + d];
      a1 += v * xfs[1 * DF + d];
      a2 += v * xfs[2 * DF + d];
      a3 += v * xfs[3 * DF + d];
      a4 += v * xfs[4 * DF + d];
    }
#pragma unroll
    for (int off = 32; off > 0; off >>= 1) {
      nrm += __shfl_xor(nrm, off);
      a0 += __shfl_xor(a0, off);
      a1 += __shfl_xor(a1, off);
      a2 += __shfl_xor(a2, off);
      a3 += __shfl_xor(a3, off);
      a4 += __shfl_xor(a4, off);
    }
    if (lane == 0 && live) {
      const float sc = 1.0f / fmaxf(sqrtf(nrm), 1e-12f);
      float* op = out + ((size_t)bb * NQ + q) * 5;
      op[0] = a0 * sc;
      op[1] = a1 * sc;
      op[2] = a2 * sc;
      op[3] = a3 * sc;
      op[4] = a4 * sc;
    }
  }
}

// =====================================================================
extern "C" void kernel_launch(void* const* d_in, const int* in_sizes, int n_in,
                              void* d_out, int out_size, void* d_ws,
                              size_t ws_size, hipStream_t stream) {
  const float* ftest = (const float*)d_in[0];
  const float* ftrain = (const float*)d_in[1];
  const int* usimple = (const int*)d_in[4];
  float* out = (float*)d_out;
  const int B = in_sizes[1] / (NSUP * DF);

  qp_kernel<<<dim3((B + 1) / 2), dim3(TPB), 0, stream>>>(ftrain, ftest,
                                                         usimple, out, B);
}